// Round 1
// baseline (82.754 us; speedup 1.0000x reference)
//
#include <hip/hip_runtime.h>
#include <math.h>

// Problem constants (TemporalAttentionModule): B=8, F=128, K=256, E=256, alpha=0.2
#define BB 8
#define FF 128
#define KK 256
#define EE 256
#define TK 8   // k-rows per block in pq_kernel
#define TI 4   // i-rows per block in attn_kernel

// Kernel 1: p[b,k,e] = sum_f x[b,f,k]*W[f,e] + b_lin[e];  q[b,k,e] = sum_f x[b,f,k]*W[F+f,e]
// Block handles TK consecutive k for one b; thread = e. x reads are block-uniform -> s_load.
__global__ __launch_bounds__(256) void pq_kernel(
    const float* __restrict__ x, const float* __restrict__ W,
    const float* __restrict__ b_lin, float* __restrict__ p, float* __restrict__ q) {
  const int b  = blockIdx.x / (KK / TK);
  const int k0 = (blockIdx.x % (KK / TK)) * TK;
  const int e  = threadIdx.x;
  float pacc[TK], qacc[TK];
#pragma unroll
  for (int t = 0; t < TK; ++t) { pacc[t] = 0.f; qacc[t] = 0.f; }
  const float* xb = x + b * FF * KK + k0;
#pragma unroll 4
  for (int f = 0; f < FF; ++f) {
    const float w1 = W[f * EE + e];          // coalesced across lanes
    const float w2 = W[(FF + f) * EE + e];
#pragma unroll
    for (int t = 0; t < TK; ++t) {
      const float v = xb[f * KK + t];        // uniform -> scalar load
      pacc[t] = fmaf(v, w1, pacc[t]);
      qacc[t] = fmaf(v, w2, qacc[t]);
    }
  }
  const float bl = b_lin[e];
#pragma unroll
  for (int t = 0; t < TK; ++t) {
    p[(b * KK + k0 + t) * EE + e] = pacc[t] + bl;   // coalesced
    q[(b * KK + k0 + t) * EE + e] = qacc[t];
  }
}

// Kernel 2: fused scores + softmax + PV for TI i-rows per block.
// Phase 1: thread j computes e[b,i,j] for t=0..TI-1 (q per-thread stream, p/a uniform)
// Phase 2: wave w does softmax of row i0+w (shfl_xor reduce over 64 lanes)
// Phase 3: wave w computes out row i0+w over f (attn uniform LDS broadcast)
__global__ __launch_bounds__(256) void attn_kernel(
    const float* __restrict__ x, const float* __restrict__ p,
    const float* __restrict__ q, const float* __restrict__ a,
    const float* __restrict__ bias, float* __restrict__ out) {
  __shared__ float sc[TI][KK];    // scores -> attn weights
  __shared__ float res[FF][TI];   // transposed sigmoid outputs for coalesced store

  const int b  = blockIdx.x / (KK / TI);
  const int i0 = (blockIdx.x % (KK / TI)) * TI;
  const int j  = threadIdx.x;

  // ---- Phase 1: scores ----
  float acc[TI];
#pragma unroll
  for (int t = 0; t < TI; ++t) acc[t] = 0.f;
  const float* qrow = q + (b * KK + j) * EE;
  const float* prow = p + (b * KK + i0) * EE;   // uniform base
  for (int e4 = 0; e4 < EE; e4 += 4) {
    const float4 qv = *(const float4*)(qrow + e4);
    const float4 av = *(const float4*)(a + e4);          // uniform
#pragma unroll
    for (int t = 0; t < TI; ++t) {
      const float4 pv = *(const float4*)(prow + t * EE + e4);  // uniform
      float sx = pv.x + qv.x; sx = fmaxf(sx, 0.2f * sx);
      float sy = pv.y + qv.y; sy = fmaxf(sy, 0.2f * sy);
      float sz = pv.z + qv.z; sz = fmaxf(sz, 0.2f * sz);
      float sw = pv.w + qv.w; sw = fmaxf(sw, 0.2f * sw);
      acc[t] = fmaf(sx, av.x, acc[t]);
      acc[t] = fmaf(sy, av.y, acc[t]);
      acc[t] = fmaf(sz, av.z, acc[t]);
      acc[t] = fmaf(sw, av.w, acc[t]);
    }
  }
#pragma unroll
  for (int t = 0; t < TI; ++t)
    sc[t][j] = acc[t] + bias[(i0 + t) * KK + j];   // coalesced bias read
  __syncthreads();

  // ---- Phase 2: softmax (wave w owns row w) ----
  const int w    = threadIdx.x >> 6;
  const int lane = threadIdx.x & 63;
  {
    float v0 = sc[w][lane], v1 = sc[w][lane + 64],
          v2 = sc[w][lane + 128], v3 = sc[w][lane + 192];
    float m = fmaxf(fmaxf(v0, v1), fmaxf(v2, v3));
#pragma unroll
    for (int off = 32; off; off >>= 1) m = fmaxf(m, __shfl_xor(m, off, 64));
    float e0 = __expf(v0 - m), e1 = __expf(v1 - m),
          e2 = __expf(v2 - m), e3 = __expf(v3 - m);
    float s = e0 + e1 + e2 + e3;
#pragma unroll
    for (int off = 32; off; off >>= 1) s += __shfl_xor(s, off, 64);
    const float inv = 1.f / s;
    sc[w][lane] = e0 * inv; sc[w][lane + 64]  = e1 * inv;
    sc[w][lane + 128] = e2 * inv; sc[w][lane + 192] = e3 * inv;
  }
  __syncthreads();

  // ---- Phase 3: PV + sigmoid ----
  {
    const float* xb = x + b * FF * KK;
    float acc0 = 0.f, acc1 = 0.f;
    for (int j4 = 0; j4 < KK; j4 += 4) {
      const float4 at = *(const float4*)&sc[w][j4];             // uniform broadcast
      const float4 xa = *(const float4*)(xb + lane * KK + j4);
      const float4 xc = *(const float4*)(xb + (lane + 64) * KK + j4);
      acc0 = fmaf(at.x, xa.x, acc0); acc0 = fmaf(at.y, xa.y, acc0);
      acc0 = fmaf(at.z, xa.z, acc0); acc0 = fmaf(at.w, xa.w, acc0);
      acc1 = fmaf(at.x, xc.x, acc1); acc1 = fmaf(at.y, xc.y, acc1);
      acc1 = fmaf(at.z, xc.z, acc1); acc1 = fmaf(at.w, xc.w, acc1);
    }
    res[lane][w]      = 1.f / (1.f + __expf(-acc0));
    res[lane + 64][w] = 1.f / (1.f + __expf(-acc1));
  }
  __syncthreads();

  // ---- transposed coalesced store: out[b, f, i0..i0+3] ----
  if (threadIdx.x < FF) {
    const int f = threadIdx.x;
    const float4 o = *(const float4*)&res[f][0];
    *(float4*)(out + (b * FF + f) * KK + i0) = o;
  }
}

extern "C" void kernel_launch(void* const* d_in, const int* in_sizes, int n_in,
                              void* d_out, int out_size, void* d_ws, size_t ws_size,
                              hipStream_t stream) {
  const float* x     = (const float*)d_in[0];
  const float* W     = (const float*)d_in[1];
  const float* b_lin = (const float*)d_in[2];
  const float* a     = (const float*)d_in[3];
  const float* bias  = (const float*)d_in[4];
  float* out = (float*)d_out;

  float* p = (float*)d_ws;                 // [B,K,E] f32, 2 MB (b_lin folded in)
  float* q = p + BB * KK * EE;             // [B,K,E] f32, 2 MB

  pq_kernel<<<BB * KK / TK, 256, 0, stream>>>(x, W, b_lin, p, q);
  attn_kernel<<<BB * KK / TI, 256, 0, stream>>>(x, p, q, a, bias, out);
}

// Round 2
// 55.497 us; speedup vs baseline: 1.4912x; 1.4912x over previous
//
#include <hip/hip_runtime.h>
#include <math.h>

// B=8, F=128, K=256, E=256, alpha=0.2
#define BB 8
#define FF 128
#define KK 256
#define EE 256
#define TI 8

typedef float f4 __attribute__((ext_vector_type(4)));

__device__ __forceinline__ float rdl(float v, int l) {
  return __int_as_float(__builtin_amdgcn_readlane(__float_as_int(v), l));
}

// p[b,k,e] = sum_f x[b,f,k] W[f,e] + b_lin[e];  q[b,k,e] = sum_f x[b,f,k] W[F+f,e]
// 256 blocks x 512 thr: thread = (e, f-half). 8 k per block.
__global__ __launch_bounds__(512) void pq_kernel(
    const float* __restrict__ x, const float* __restrict__ W,
    const float* __restrict__ b_lin, float* __restrict__ p, float* __restrict__ q) {
  __shared__ float part[16][KK];
  const int b  = blockIdx.x >> 5;
  const int k0 = (blockIdx.x & 31) * 8;
  const int e  = threadIdx.x & 255;
  const int fh = threadIdx.x >> 8;

  float pacc[8] = {0,0,0,0,0,0,0,0}, qacc[8] = {0,0,0,0,0,0,0,0};
  const float* xb = x + b * FF * KK + k0;  // + f*KK
  const int f0 = fh * 64;

  f4 xv0 = *(const f4*)(xb + f0 * KK);
  f4 xv1 = *(const f4*)(xb + f0 * KK + 4);
#pragma unroll 4
  for (int ff = 0; ff < 64; ++ff) {
    const int f  = f0 + ff;
    const int fn = f0 + ((ff + 1) & 63);
    // prefetch next x chunk (uniform -> scalar loads)
    f4 xn0 = *(const f4*)(xb + fn * KK);
    f4 xn1 = *(const f4*)(xb + fn * KK + 4);
    const float w1 = W[f * EE + e];          // coalesced
    const float w2 = W[(FF + f) * EE + e];
#pragma unroll
    for (int t = 0; t < 4; ++t) {
      pacc[t]     = fmaf(xv0[t], w1, pacc[t]);
      qacc[t]     = fmaf(xv0[t], w2, qacc[t]);
      pacc[4 + t] = fmaf(xv1[t], w1, pacc[4 + t]);
      qacc[4 + t] = fmaf(xv1[t], w2, qacc[4 + t]);
    }
    xv0 = xn0; xv1 = xn1;
  }

  if (fh == 1) {
#pragma unroll
    for (int t = 0; t < 8; ++t) { part[t][e] = pacc[t]; part[8 + t][e] = qacc[t]; }
  }
  __syncthreads();
  if (fh == 0) {
    const float bl = b_lin[e];
#pragma unroll
    for (int t = 0; t < 8; ++t) {
      p[(b * KK + k0 + t) * EE + e] = pacc[t] + part[t][e] + bl;
      q[(b * KK + k0 + t) * EE + e] = qacc[t] + part[8 + t][e];
    }
  }
}

// 256 blocks x 512 thr. Block = (b, i-tile of 8).
// Phase 1: thread (j, e-half) -> 8 partial scores; LDS combine + bias.
// Phase 2: wave w softmaxes row w.
// Phase 3: wave (ih,fh,jh): i-set {4ih..}, f in [64fh,+64) (lane=f), j-half;
//          attn broadcast via v_readlane, x streamed per-lane from L2/L1.
__global__ __launch_bounds__(512) void attn_kernel(
    const float* __restrict__ x, const float* __restrict__ p,
    const float* __restrict__ q, const float* __restrict__ a,
    const float* __restrict__ bias, float* __restrict__ out) {
  __shared__ float psum[TI][KK];
  __shared__ float sc[TI][KK];
  __shared__ f4 part[4][64];
  __shared__ float res[FF][12];

  const int b  = blockIdx.x >> 5;
  const int i0 = (blockIdx.x & 31) * TI;
  const int j  = threadIdx.x & 255;
  const int eh = threadIdx.x >> 8;

  // ---- Phase 1: partial scores over e-half ----
  float acc[TI] = {0,0,0,0,0,0,0,0};
  {
    const float* qrow = q + (b * KK + j) * EE + eh * 128;
    const float* pb   = p + (b * KK + i0) * EE + eh * 128;  // + i*EE + e
    const float* ab   = a + eh * 128;
    f4 qv = *(const f4*)qrow;
    f4 av = *(const f4*)ab;
    f4 pv[TI];
#pragma unroll
    for (int i = 0; i < TI; ++i) pv[i] = *(const f4*)(pb + i * EE);
#pragma unroll 2
    for (int c = 0; c < 32; ++c) {
      const int cn = ((c + 1) & 31) * 4;
      f4 qn = *(const f4*)(qrow + cn);      // per-lane stream
      f4 an = *(const f4*)(ab + cn);        // uniform
      f4 pn[TI];
#pragma unroll
      for (int i = 0; i < TI; ++i) pn[i] = *(const f4*)(pb + i * EE + cn);  // uniform
#pragma unroll
      for (int i = 0; i < TI; ++i) {
#pragma unroll
        for (int u = 0; u < 4; ++u) {
          float s = pv[i][u] + qv[u];
          s = fmaxf(s, 0.2f * s);
          acc[i] = fmaf(s, av[u], acc[i]);
        }
      }
      qv = qn; av = an;
#pragma unroll
      for (int i = 0; i < TI; ++i) pv[i] = pn[i];
    }
  }
  if (eh == 1) {
#pragma unroll
    for (int i = 0; i < TI; ++i) psum[i][j] = acc[i];
  }
  __syncthreads();
  if (eh == 0) {
#pragma unroll
    for (int i = 0; i < TI; ++i)
      sc[i][j] = acc[i] + psum[i][j] + bias[(i0 + i) * KK + j];
  }
  __syncthreads();

  // ---- Phase 2: softmax, wave w owns row w ----
  const int w    = threadIdx.x >> 6;
  const int lane = threadIdx.x & 63;
  {
    f4 v = *(const f4*)&sc[w][4 * lane];
    float m = fmaxf(fmaxf(v[0], v[1]), fmaxf(v[2], v[3]));
#pragma unroll
    for (int off = 32; off; off >>= 1) m = fmaxf(m, __shfl_xor(m, off, 64));
    f4 ev;
#pragma unroll
    for (int u = 0; u < 4; ++u) ev[u] = __expf(v[u] - m);
    float s = ev[0] + ev[1] + ev[2] + ev[3];
#pragma unroll
    for (int off = 32; off; off >>= 1) s += __shfl_xor(s, off, 64);
    const float inv = 1.f / s;
#pragma unroll
    for (int u = 0; u < 4; ++u) ev[u] *= inv;
    *(f4*)&sc[w][4 * lane] = ev;
  }
  __syncthreads();

  // ---- Phase 3: PV ----
  const int ih  = w & 1;          // i-set {4ih..4ih+3}
  const int fh2 = (w >> 1) & 1;   // f in [64*fh2, +64), lane = f offset
  const int jh  = w >> 2;         // j-half
  {
    f4 at[4];
#pragma unroll
    for (int r = 0; r < 4; ++r) at[r] = *(const f4*)&sc[4 * ih + r][4 * lane];
    const int f = fh2 * 64 + lane;
    const float* xr = x + (b * FF + f) * KK;
    float pr[4] = {0, 0, 0, 0};
    for (int c = 32 * jh; c < 32 * jh + 32; ++c) {
      f4 xv = *(const f4*)(xr + 4 * c);   // per-lane sequential stream
#pragma unroll
      for (int r = 0; r < 4; ++r) {
        pr[r] = fmaf(rdl(at[r][0], c), xv[0], pr[r]);
        pr[r] = fmaf(rdl(at[r][1], c), xv[1], pr[r]);
        pr[r] = fmaf(rdl(at[r][2], c), xv[2], pr[r]);
        pr[r] = fmaf(rdl(at[r][3], c), xv[3], pr[r]);
      }
    }
    if (jh == 1) {
      f4 t; t[0] = pr[0]; t[1] = pr[1]; t[2] = pr[2]; t[3] = pr[3];
      part[w & 3][lane] = t;
    }
    __syncthreads();
    if (jh == 0) {
      f4 o = part[w][lane];
#pragma unroll
      for (int r = 0; r < 4; ++r) {
        float v = pr[r] + o[r];
        res[f][4 * ih + r] = 1.f / (1.f + __expf(-v));
      }
    }
  }
  __syncthreads();

  // ---- coalesced store: out[b, f, i0..i0+7] ----
  if (threadIdx.x < 256) {
    const int fo = threadIdx.x >> 1;
    const int ic = (threadIdx.x & 1) * 4;
    f4 o;
#pragma unroll
    for (int u = 0; u < 4; ++u) o[u] = res[fo][ic + u];
    *(f4*)(out + (b * FF + fo) * KK + i0 + ic) = o;
  }
}

extern "C" void kernel_launch(void* const* d_in, const int* in_sizes, int n_in,
                              void* d_out, int out_size, void* d_ws, size_t ws_size,
                              hipStream_t stream) {
  const float* x     = (const float*)d_in[0];
  const float* W     = (const float*)d_in[1];
  const float* b_lin = (const float*)d_in[2];
  const float* a     = (const float*)d_in[3];
  const float* bias  = (const float*)d_in[4];
  float* out = (float*)d_out;

  float* p = (float*)d_ws;            // [B,K,E] f32 (b_lin folded)
  float* q = p + BB * KK * EE;        // [B,K,E] f32

  pq_kernel<<<BB * KK / 8, 512, 0, stream>>>(x, W, b_lin, p, q);
  attn_kernel<<<BB * KK / TI, 512, 0, stream>>>(x, p, q, a, bias, out);
}

// Round 3
// 40.168 us; speedup vs baseline: 2.0602x; 1.3816x over previous
//
#include <hip/hip_runtime.h>
#include <math.h>

// B=8, F=128, K=256, E=256, alpha=0.2
#define BB 8
#define FF 128
#define KK 256
#define EE 256
#define TI 4

typedef float f4 __attribute__((ext_vector_type(4)));
typedef float f2 __attribute__((ext_vector_type(2)));

// ---------------------------------------------------------------------------
// prep: p[b][k][e] = sum_f x[b,f,k] W[f,e] + b_lin[e]   (row-major, 2MB)
//       qT[b][e][k] = sum_f x[b,f,k] W[F+f,e]           (transposed, 2MB)
//       xT[b][k][f] = x[b][f][k]                        (1MB)
//       Q6[b][k]    = 0.6 * sum_e a[e]*q[b][k][e]       (8KB)
// grid 256 blocks (b, k-octet) x 512 threads (e, f-half)
// ---------------------------------------------------------------------------
__global__ __launch_bounds__(512, 2) void prep_kernel(
    const float* __restrict__ x, const float* __restrict__ W,
    const float* __restrict__ b_lin, const float* __restrict__ a,
    float* __restrict__ p, float* __restrict__ qT,
    float* __restrict__ xT, float* __restrict__ Q6) {
  __shared__ float xs[FF][8];      // x-tile [f][k-octet], 4KB (b128-aligned rows)
  __shared__ float part[16][EE];   // partials / q staging, 16KB

  const int b  = blockIdx.x >> 5;
  const int k0 = (blockIdx.x & 31) * 8;
  const int t  = threadIdx.x;

  // stage x[b][:][k0..k0+7] -> LDS (semi-coalesced 32B segments, one-time)
  {
    const float* xb = x + b * FF * KK + k0;
    const int f = t >> 3, u = t & 7;
    xs[f][u]      = xb[f * KK + u];
    xs[f + 64][u] = xb[(f + 64) * KK + u];
  }
  __syncthreads();

  // write xT[b][k0+u][:] (coalesced 8B/lane; LDS column reads are one-time)
  {
    const int u = t >> 6, f2i = (t & 63) * 2;
    f2 v; v.x = xs[f2i][u]; v.y = xs[f2i + 1][u];
    *(f2*)&xT[(b * KK + k0 + u) * FF + f2i] = v;
  }

  const int e = t & 255, fh = t >> 8;
  float pacc[8] = {0,0,0,0,0,0,0,0}, qacc[8] = {0,0,0,0,0,0,0,0};
  {
    const float* Wp = W + (fh * 64) * EE + e;
    const float* Wq = W + (FF + fh * 64) * EE + e;
    const float* xr = &xs[fh * 64][0];
#pragma unroll 8
    for (int ff = 0; ff < 64; ++ff) {
      const float w1 = Wp[ff * EE];               // coalesced, L2-hot
      const float w2 = Wq[ff * EE];
      const f4 xv0 = *(const f4*)(xr + ff * 8);    // uniform LDS b128
      const f4 xv1 = *(const f4*)(xr + ff * 8 + 4);
#pragma unroll
      for (int u = 0; u < 4; ++u) {
        pacc[u]     = fmaf(xv0[u], w1, pacc[u]);
        qacc[u]     = fmaf(xv0[u], w2, qacc[u]);
        pacc[4 + u] = fmaf(xv1[u], w1, pacc[4 + u]);
        qacc[4 + u] = fmaf(xv1[u], w2, qacc[4 + u]);
      }
    }
  }

  if (fh == 1) {
#pragma unroll
    for (int u = 0; u < 8; ++u) { part[u][e] = pacc[u]; part[8 + u][e] = qacc[u]; }
  }
  __syncthreads();
  if (fh == 0) {
    const float bl = b_lin[e], ae = a[e];
#pragma unroll
    for (int u = 0; u < 8; ++u) {
      const float pv = pacc[u] + part[u][e] + bl;
      const float qv = qacc[u] + part[8 + u][e];
      p[(b * KK + k0 + u) * EE + e] = pv;
      part[u][e]     = ae * qv;   // for Q6 reduce (same-thread column, no race)
      part[8 + u][e] = qv;        // for qT write
    }
  }
  __syncthreads();

  // qT[b][e][k0..k0+7]: thread (e = t>>1, k-half) gathers 4 from LDS, f4 store
  {
    const int ee = t >> 1, k4 = (t & 1) * 4;
    f4 v;
#pragma unroll
    for (int u = 0; u < 4; ++u) v[u] = part[8 + k4 + u][ee];  // lane-distinct banks
    *(f4*)&qT[(b * EE + ee) * KK + k0 + k4] = v;
  }

  // Q6: wave w reduces row part[w] (= a*q for k = k0+w)
  {
    const int w = t >> 6, lane = t & 63;
    float s = part[w][lane] + part[w][lane + 64] + part[w][lane + 128] + part[w][lane + 192];
#pragma unroll
    for (int off = 32; off; off >>= 1) s += __shfl_xor(s, off, 64);
    if (lane == 0) Q6[b * KK + k0 + w] = 0.6f * s;
  }
}

// ---------------------------------------------------------------------------
// attn: scores (|s| trick) + softmax + PV + sigmoid + transposed store.
// grid 512 blocks (b, i-tile of 4) x 512 threads (j, e-half). 4 waves/SIMD.
// ---------------------------------------------------------------------------
__global__ __launch_bounds__(512, 4) void attn_kernel(
    const float* __restrict__ p, const float* __restrict__ qT,
    const float* __restrict__ xT, const float* __restrict__ Q6,
    const float* __restrict__ a, const float* __restrict__ bias,
    float* __restrict__ out) {
  __shared__ float pt[TI][EE];       // p-tile, 4KB
  __shared__ float a_s[EE];          // 1KB
  __shared__ float psum[TI][KK];     // 4KB
  __shared__ float sc[TI][KK];       // 4KB
  __shared__ float pvp[4][TI][FF];   // PV quarter partials, 8KB

  const int b  = blockIdx.x >> 6;
  const int i0 = (blockIdx.x & 63) * TI;
  const int t  = threadIdx.x;
  const int j  = t & 255, eh = t >> 8;

  // phase 0: stage p-tile + a
  if (t < 256) {
    const int i = t >> 6, e4 = (t & 63) * 4;
    *(f4*)&pt[i][e4] = *(const f4*)&p[(b * KK + i0 + i) * EE + e4];
  } else if (t < 320) {
    const int e4 = (t - 256) * 4;
    *(f4*)&a_s[e4] = *(const f4*)&a[e4];
  }
  const float q6 = Q6[b * KK + j];
  __syncthreads();

  // phase 1: acc[i] = sum_e |p_ie + q_je| * a_e   over this thread's e-half
  float acc[TI] = {0, 0, 0, 0};
  {
    const float* qTb = qT + (b * EE + eh * 128) * KK + j;  // stride KK rows
    const float* ab  = &a_s[eh * 128];
    const float* pb  = &pt[0][eh * 128];
#pragma unroll 4
    for (int c = 0; c < 32; ++c) {
      const int e4 = c * 4;
      const float q0 = qTb[(e4 + 0) * KK];   // coalesced dword across j-lanes
      const float q1 = qTb[(e4 + 1) * KK];
      const float q2 = qTb[(e4 + 2) * KK];
      const float q3 = qTb[(e4 + 3) * KK];
      const f4 av = *(const f4*)(ab + e4);   // uniform LDS b128
#pragma unroll
      for (int i = 0; i < TI; ++i) {
        const f4 pv = *(const f4*)(pb + i * EE + e4);  // uniform LDS b128
        acc[i] = fmaf(fabsf(pv[0] + q0), av[0], acc[i]);
        acc[i] = fmaf(fabsf(pv[1] + q1), av[1], acc[i]);
        acc[i] = fmaf(fabsf(pv[2] + q2), av[2], acc[i]);
        acc[i] = fmaf(fabsf(pv[3] + q3), av[3], acc[i]);
      }
    }
  }
  if (eh == 1) {
#pragma unroll
    for (int i = 0; i < TI; ++i) psum[i][j] = acc[i];
  }
  __syncthreads();
  if (eh == 0) {
#pragma unroll
    for (int i = 0; i < TI; ++i)
      sc[i][j] = 0.4f * (acc[i] + psum[i][j]) + q6 + bias[(i0 + i) * KK + j];
  }
  __syncthreads();

  // phase 2: softmax, wave w (<4) owns row w
  const int w = t >> 6, lane = t & 63;
  if (w < TI) {
    f4 v = *(const f4*)&sc[w][4 * lane];
    float m = fmaxf(fmaxf(v[0], v[1]), fmaxf(v[2], v[3]));
#pragma unroll
    for (int off = 32; off; off >>= 1) m = fmaxf(m, __shfl_xor(m, off, 64));
    f4 ev;
#pragma unroll
    for (int u = 0; u < 4; ++u) ev[u] = __expf(v[u] - m);
    float s = ev[0] + ev[1] + ev[2] + ev[3];
#pragma unroll
    for (int off = 32; off; off >>= 1) s += __shfl_xor(s, off, 64);
    const float inv = 1.f / s;
#pragma unroll
    for (int u = 0; u < 4; ++u) ev[u] *= inv;
    *(f4*)&sc[w][4 * lane] = ev;
  }
  __syncthreads();

  // phase 3: PV. wave = (jq, ihalf): j in [64*jq,+64), i in {2*ihalf, +1}.
  {
    const int jq = w & 3, ih = (w >> 2) * 2;
    float a00 = 0, a01 = 0, a10 = 0, a11 = 0;
    const float* xb = xT + (b * KK + jq * 64) * FF + 2 * lane;
    for (int jj = 0; jj < 64; ++jj) {
      const f2 xv = *(const f2*)(xb + jj * FF);   // coalesced 8B/lane
      const float s0 = sc[ih][jq * 64 + jj];      // uniform broadcast
      const float s1 = sc[ih + 1][jq * 64 + jj];
      a00 = fmaf(s0, xv.x, a00); a01 = fmaf(s0, xv.y, a01);
      a10 = fmaf(s1, xv.x, a10); a11 = fmaf(s1, xv.y, a11);
    }
    f2 r0; r0.x = a00; r0.y = a01;
    f2 r1; r1.x = a10; r1.y = a11;
    *(f2*)&pvp[jq][ih][2 * lane]     = r0;
    *(f2*)&pvp[jq][ih + 1][2 * lane] = r1;
  }
  __syncthreads();

  // combine quarters + sigmoid + store out[b][f][i0+i]
  {
    const int i = t >> 7, f = t & 127;
    const float s = pvp[0][i][f] + pvp[1][i][f] + pvp[2][i][f] + pvp[3][i][f];
    out[(b * FF + f) * KK + i0 + i] = 1.f / (1.f + __expf(-s));
  }
}

extern "C" void kernel_launch(void* const* d_in, const int* in_sizes, int n_in,
                              void* d_out, int out_size, void* d_ws, size_t ws_size,
                              hipStream_t stream) {
  const float* x     = (const float*)d_in[0];
  const float* W     = (const float*)d_in[1];
  const float* b_lin = (const float*)d_in[2];
  const float* a     = (const float*)d_in[3];
  const float* bias  = (const float*)d_in[4];
  float* out = (float*)d_out;

  float* p  = (float*)d_ws;                    // [B,K,E] 2MB
  float* qT = p  + BB * KK * EE;               // [B,E,K] 2MB
  float* xT = qT + BB * EE * KK;               // [B,K,F] 1MB
  float* Q6 = xT + BB * KK * FF;               // [B,K]   8KB

  prep_kernel<<<BB * KK / 8, 512, 0, stream>>>(x, W, b_lin, a, p, qT, xT, Q6);
  attn_kernel<<<BB * (KK / TI), 512, 0, stream>>>(p, qT, xT, Q6, a, bias, out);
}

// Round 4
// 37.691 us; speedup vs baseline: 2.1956x; 1.0657x over previous
//
#include <hip/hip_runtime.h>
#include <math.h>

// B=8, F=128, K=256, E=256, alpha=0.2
#define BB 8
#define FF 128
#define KK 256
#define EE 256
#define TI 4

typedef float f4 __attribute__((ext_vector_type(4)));
typedef float f2 __attribute__((ext_vector_type(2)));

// ---------------------------------------------------------------------------
// prep: p[b][k][e] = sum_f x[b,f,k] W[f,e] + b_lin[e]   (row-major, 2MB)
//       qT[b][e][k] = sum_f x[b,f,k] W[F+f,e]           (transposed, 2MB)
//       xT[b][k][f] = x[b][f][k]                        (1MB)
//       Q6[b][k]    = 0.6 * sum_e a[e]*q[b][k][e]       (8KB)
// grid 256 blocks (b, k-octet) x 512 threads (e, f-half)
// ---------------------------------------------------------------------------
__global__ __launch_bounds__(512, 2) void prep_kernel(
    const float* __restrict__ x, const float* __restrict__ W,
    const float* __restrict__ b_lin, const float* __restrict__ a,
    float* __restrict__ p, float* __restrict__ qT,
    float* __restrict__ xT, float* __restrict__ Q6) {
  __shared__ float xs[FF][8];      // x-tile [f][k-octet], 4KB
  __shared__ float part[16][EE];   // partials / q staging, 16KB

  const int b  = blockIdx.x >> 5;
  const int k0 = (blockIdx.x & 31) * 8;
  const int t  = threadIdx.x;

  // stage x[b][:][k0..k0+7] -> LDS
  {
    const float* xb = x + b * FF * KK + k0;
    const int f = t >> 3, u = t & 7;
    xs[f][u]      = xb[f * KK + u];
    xs[f + 64][u] = xb[(f + 64) * KK + u];
  }
  __syncthreads();

  // write xT[b][k0+u][:]
  {
    const int u = t >> 6, f2i = (t & 63) * 2;
    f2 v; v.x = xs[f2i][u]; v.y = xs[f2i + 1][u];
    *(f2*)&xT[(b * KK + k0 + u) * FF + f2i] = v;
  }

  const int e = t & 255, fh = t >> 8;
  float pacc[8] = {0,0,0,0,0,0,0,0}, qacc[8] = {0,0,0,0,0,0,0,0};
  {
    const float* Wp = W + (fh * 64) * EE + e;
    const float* Wq = W + (FF + fh * 64) * EE + e;
    const float* xr = &xs[fh * 64][0];
#pragma unroll 8
    for (int ff = 0; ff < 64; ++ff) {
      const float w1 = Wp[ff * EE];
      const float w2 = Wq[ff * EE];
      const f4 xv0 = *(const f4*)(xr + ff * 8);
      const f4 xv1 = *(const f4*)(xr + ff * 8 + 4);
#pragma unroll
      for (int u = 0; u < 4; ++u) {
        pacc[u]     = fmaf(xv0[u], w1, pacc[u]);
        qacc[u]     = fmaf(xv0[u], w2, qacc[u]);
        pacc[4 + u] = fmaf(xv1[u], w1, pacc[4 + u]);
        qacc[4 + u] = fmaf(xv1[u], w2, qacc[4 + u]);
      }
    }
  }

  if (fh == 1) {
#pragma unroll
    for (int u = 0; u < 8; ++u) { part[u][e] = pacc[u]; part[8 + u][e] = qacc[u]; }
  }
  __syncthreads();
  if (fh == 0) {
    const float bl = b_lin[e], ae = a[e];
#pragma unroll
    for (int u = 0; u < 8; ++u) {
      const float pv = pacc[u] + part[u][e] + bl;
      const float qv = qacc[u] + part[8 + u][e];
      p[(b * KK + k0 + u) * EE + e] = pv;
      part[u][e]     = ae * qv;
      part[8 + u][e] = qv;
    }
  }
  __syncthreads();

  // qT[b][e][k0..k0+7]
  {
    const int ee = t >> 1, k4 = (t & 1) * 4;
    f4 v;
#pragma unroll
    for (int u = 0; u < 4; ++u) v[u] = part[8 + k4 + u][ee];
    *(f4*)&qT[(b * EE + ee) * KK + k0 + k4] = v;
  }

  // Q6: wave w reduces row part[w]
  {
    const int w = t >> 6, lane = t & 63;
    float s = part[w][lane] + part[w][lane + 64] + part[w][lane + 128] + part[w][lane + 192];
#pragma unroll
    for (int off = 32; off; off >>= 1) s += __shfl_xor(s, off, 64);
    if (lane == 0) Q6[b * KK + k0 + w] = 0.6f * s;
  }
}

// ---------------------------------------------------------------------------
// attn: scores (|s| trick, JT=4 j's per lane) + softmax + PV + sigmoid.
// grid 512 blocks (b, i-tile of 4) x 512 threads = 8 waves (eq in 4, ih in 2).
// lane owns j in {4*lane .. 4*lane+3}  ->  qT loads are b128 coalesced.
// ---------------------------------------------------------------------------
__global__ __launch_bounds__(512, 4) void attn_kernel(
    const float* __restrict__ p, const float* __restrict__ qT,
    const float* __restrict__ xT, const float* __restrict__ Q6,
    const float* __restrict__ a, const float* __restrict__ bias,
    float* __restrict__ out) {
  __shared__ float pt[TI][EE];        // 4KB
  __shared__ float a_s[EE];           // 1KB
  __shared__ float psum[3][TI][KK];   // 12KB
  __shared__ float sc[TI][KK];        // 4KB
  __shared__ float pvp[4][TI][FF];    // 8KB

  const int b    = blockIdx.x >> 6;
  const int i0   = (blockIdx.x & 63) * TI;
  const int t    = threadIdx.x;
  const int lane = t & 63;
  const int w    = t >> 6;
  const int eq   = w & 3;    // e-quarter
  const int ih   = w >> 2;   // i-half

  // ---- phase 0: stage p-tile (+b_lin already folded) and a ----
  if (t < 256) {
    const int i = t >> 6, e4 = (t & 63) * 4;
    *(f4*)&pt[i][e4] = *(const f4*)&p[(b * KK + i0 + i) * EE + e4];
  } else if (t < 320) {
    const int e4 = (t - 256) * 4;
    *(f4*)&a_s[e4] = *(const f4*)&a[e4];
  }
  __syncthreads();

  // ---- phase 1: acc[i][v] = sum_e |p_ie + q_{j=4l+v,e}| * a_e over e-quarter
  f4 acc0 = {0.f, 0.f, 0.f, 0.f}, acc1 = {0.f, 0.f, 0.f, 0.f};
  {
    const int e0 = eq * 64;
    const float* qc = qT + (b * EE + e0) * KK + 4 * lane;
    const float* ab = &a_s[e0];
    const float* p0 = &pt[2 * ih][e0];
    const float* p1 = &pt[2 * ih + 1][e0];
#pragma unroll 2
    for (int c = 0; c < 16; ++c) {
      const int e4 = 4 * c;
      const f4 q0 = *(const f4*)(qc);            // e = e0+4c+0, j = 4l..4l+3
      const f4 q1 = *(const f4*)(qc + KK);       // imm-offset friendly
      const f4 q2 = *(const f4*)(qc + 2 * KK);
      const f4 q3 = *(const f4*)(qc + 3 * KK);
      const f4 av  = *(const f4*)(ab + e4);      // uniform LDS b128
      const f4 pv0 = *(const f4*)(p0 + e4);      // uniform LDS b128
      const f4 pv1 = *(const f4*)(p1 + e4);
#pragma unroll
      for (int v = 0; v < 4; ++v) {
        acc0[v] = fmaf(fabsf(pv0[0] + q0[v]), av[0], acc0[v]);  // abs folds to VOP3 mod
        acc0[v] = fmaf(fabsf(pv0[1] + q1[v]), av[1], acc0[v]);
        acc0[v] = fmaf(fabsf(pv0[2] + q2[v]), av[2], acc0[v]);
        acc0[v] = fmaf(fabsf(pv0[3] + q3[v]), av[3], acc0[v]);
        acc1[v] = fmaf(fabsf(pv1[0] + q0[v]), av[0], acc1[v]);
        acc1[v] = fmaf(fabsf(pv1[1] + q1[v]), av[1], acc1[v]);
        acc1[v] = fmaf(fabsf(pv1[2] + q2[v]), av[2], acc1[v]);
        acc1[v] = fmaf(fabsf(pv1[3] + q3[v]), av[3], acc1[v]);
      }
      qc += 4 * KK;
    }
  }
  if (eq != 0) {
    *(f4*)&psum[eq - 1][2 * ih][4 * lane]     = acc0;
    *(f4*)&psum[eq - 1][2 * ih + 1][4 * lane] = acc1;
  }
  __syncthreads();
  if (eq == 0) {
    const f4 q6 = *(const f4*)&Q6[b * KK + 4 * lane];
#pragma unroll
    for (int r = 0; r < 2; ++r) {
      const int i = 2 * ih + r;
      const f4 s0 = (r == 0) ? acc0 : acc1;
      const f4 s1 = *(const f4*)&psum[0][i][4 * lane];
      const f4 s2 = *(const f4*)&psum[1][i][4 * lane];
      const f4 s3 = *(const f4*)&psum[2][i][4 * lane];
      const f4 bv = *(const f4*)&bias[(i0 + i) * KK + 4 * lane];
      f4 o;
#pragma unroll
      for (int u = 0; u < 4; ++u)
        o[u] = 0.4f * (s0[u] + s1[u] + s2[u] + s3[u]) + q6[u] + bv[u];
      *(f4*)&sc[i][4 * lane] = o;
    }
  }
  __syncthreads();

  // ---- phase 2: softmax, wave w (<4) owns row w ----
  if (w < TI) {
    f4 v = *(const f4*)&sc[w][4 * lane];
    float m = fmaxf(fmaxf(v[0], v[1]), fmaxf(v[2], v[3]));
#pragma unroll
    for (int off = 32; off; off >>= 1) m = fmaxf(m, __shfl_xor(m, off, 64));
    f4 ev;
#pragma unroll
    for (int u = 0; u < 4; ++u) ev[u] = __expf(v[u] - m);
    float s = ev[0] + ev[1] + ev[2] + ev[3];
#pragma unroll
    for (int off = 32; off; off >>= 1) s += __shfl_xor(s, off, 64);
    const float inv = 1.f / s;
#pragma unroll
    for (int u = 0; u < 4; ++u) ev[u] *= inv;
    *(f4*)&sc[w][4 * lane] = ev;
  }
  __syncthreads();

  // ---- phase 3: PV. wave (jq, ih): j in [64jq,+64), i in {2ih,2ih+1} ----
  {
    const int jq = w & 3, ia = 2 * (w >> 2), ib = ia + 1;
    float a00 = 0, a01 = 0, a10 = 0, a11 = 0;
    const float* xb = xT + (b * KK + jq * 64) * FF + 2 * lane;
    const float* sa = &sc[ia][jq * 64];
    const float* sb = &sc[ib][jq * 64];
#pragma unroll 2
    for (int g = 0; g < 16; ++g) {
      const f4 sA = *(const f4*)(sa + 4 * g);   // uniform LDS b128
      const f4 sB = *(const f4*)(sb + 4 * g);
#pragma unroll
      for (int m = 0; m < 4; ++m) {
        const f2 xv = *(const f2*)(xb + m * FF);  // coalesced 8B/lane
        a00 = fmaf(sA[m], xv.x, a00); a01 = fmaf(sA[m], xv.y, a01);
        a10 = fmaf(sB[m], xv.x, a10); a11 = fmaf(sB[m], xv.y, a11);
      }
      xb += 4 * FF;
    }
    f2 r0; r0.x = a00; r0.y = a01;
    f2 r1; r1.x = a10; r1.y = a11;
    *(f2*)&pvp[jq][ia][2 * lane] = r0;
    *(f2*)&pvp[jq][ib][2 * lane] = r1;
  }
  __syncthreads();

  // ---- combine quarters + sigmoid + store ----
  {
    const int i = t >> 7, f = t & 127;
    const float s = pvp[0][i][f] + pvp[1][i][f] + pvp[2][i][f] + pvp[3][i][f];
    out[(b * FF + f) * KK + i0 + i] = 1.f / (1.f + __expf(-s));
  }
}

extern "C" void kernel_launch(void* const* d_in, const int* in_sizes, int n_in,
                              void* d_out, int out_size, void* d_ws, size_t ws_size,
                              hipStream_t stream) {
  const float* x     = (const float*)d_in[0];
  const float* W     = (const float*)d_in[1];
  const float* b_lin = (const float*)d_in[2];
  const float* a     = (const float*)d_in[3];
  const float* bias  = (const float*)d_in[4];
  float* out = (float*)d_out;

  float* p  = (float*)d_ws;                    // [B,K,E] 2MB
  float* qT = p  + BB * KK * EE;               // [B,E,K] 2MB
  float* xT = qT + BB * EE * KK;               // [B,K,F] 1MB
  float* Q6 = xT + BB * KK * FF;               // [B,K]   8KB

  prep_kernel<<<BB * KK / 8, 512, 0, stream>>>(x, W, b_lin, a, p, qT, xT, Q6);
  attn_kernel<<<BB * (KK / TI), 512, 0, stream>>>(p, qT, xT, Q6, a, bias, out);
}